// Round 7
// baseline (124.994 us; speedup 1.0000x reference)
//
#include <hip/hip_runtime.h>

// SemanticRenderer: out[r, c] = sum_{i: ray_indices[i]==r} weights[i] * semantics[i, c]
// semantics: [N, 32] f32, weights: [N] f32, ray_indices: [N] int32 (SORTED), out: [R, 32] f32
//
// Sample-centric single-pass design:
//   memset(out, 0)  (covers empty rays + poison; atomic base)
//   render: one wave per 256-sample chunk. Perfectly balanced, all loads dense
//   and coalesced (1 KiB/wave-step), no dependent bounds loads. Run boundaries
//   within the chunk found wave-uniformly via 4 ballots + ctz. Interior runs
//   (ray fully inside chunk) -> sole writer -> plain NT store. Runs touching a
//   chunk edge whose ray continues across it -> atomicAdd f32 (device scope).
//   lane = 8*g + q: g = sample subgroup, q = float4 class quad.

typedef float f32x4 __attribute__((ext_vector_type(4)));

#define CHUNK 256

__global__ __launch_bounds__(256) void SemanticRenderer_70205535421052_kernel(
    const f32x4* __restrict__ sem4,    // [N*8] (N rows of 8 float4)
    const float* __restrict__ w,       // [N]
    const int*   __restrict__ ridx,    // [N] sorted ray ids
    float*       __restrict__ out,     // [R*32], pre-zeroed
    int N)
{
    const int wave = threadIdx.x >> 6;
    const int lane = threadIdx.x & 63;
    const int q    = lane & 7;          // class quad (classes 4q..4q+3)
    const int g    = lane >> 3;         // sample subgroup 0..7
    const int wid  = blockIdx.x * 4 + wave;
    const int base = wid * CHUNK;
    if (base >= N) return;
    const int CL = min(CHUNK, N - base);   // chunk length (256 except tail)

    // ids for positions 4*lane + {0,1,2,3}; tail positions clamped (no spurious
    // boundaries: clamped slots replicate ids[CL-1])
    int4 v;
    if (CL == CHUNK) {
        v = *reinterpret_cast<const int4*>(ridx + base + 4 * lane);
    } else {
        const int i0 = min(4 * lane,     CL - 1);
        const int i1 = min(4 * lane + 1, CL - 1);
        const int i2 = min(4 * lane + 2, CL - 1);
        const int i3 = min(4 * lane + 3, CL - 1);
        v.x = ridx[base + i0]; v.y = ridx[base + i1];
        v.z = ridx[base + i2]; v.w = ridx[base + i3];
    }
    const int prev_id = (base > 0)      ? ridx[base - 1]  : -1;
    const int next_id = (base + CL < N) ? ridx[base + CL] : -1;

    // boundary masks: position p starts a new run iff ids[p] != ids[p-1]
    const int leftw = __shfl_up(v.w, 1, 64);
    const int lft   = (lane == 0) ? prev_id : leftw;
    const unsigned long long m0 = __ballot(v.x != lft);   // positions 4*l
    const unsigned long long m1 = __ballot(v.y != v.x);   // positions 4*l+1
    const unsigned long long m2 = __ballot(v.z != v.y);   // positions 4*l+2
    const unsigned long long m3 = __ballot(v.w != v.z);   // positions 4*l+3

    int a = 0;                          // current run start (wave-uniform)
    while (a < CL) {
        // next boundary > a (smallest position t; CL if none)
        int t = CL;
        {   // j = 0: smallest l with 4l > a  ->  l >= (a+4)>>2
            const int h = (a + 4) >> 2;
            const unsigned long long mm = (h < 64) ? (m0 >> h) : 0ULL;
            if (mm) { const int c = 4 * (h + __builtin_ctzll(mm));     if (c < t) t = c; }
        }
        {   // j = 1
            const int h = (a + 3) >> 2;
            const unsigned long long mm = (h < 64) ? (m1 >> h) : 0ULL;
            if (mm) { const int c = 4 * (h + __builtin_ctzll(mm)) + 1; if (c < t) t = c; }
        }
        {   // j = 2
            const int h = (a + 2) >> 2;
            const unsigned long long mm = (h < 64) ? (m2 >> h) : 0ULL;
            if (mm) { const int c = 4 * (h + __builtin_ctzll(mm)) + 2; if (c < t) t = c; }
        }
        {   // j = 3
            const int h = (a + 1) >> 2;
            const unsigned long long mm = (h < 64) ? (m3 >> h) : 0ULL;
            if (mm) { const int c = 4 * (h + __builtin_ctzll(mm)) + 3; if (c < t) t = c; }
        }
        const int b   = t;
        const int rid = ridx[base + a];   // broadcast (L1: line already loaded)

        // accumulate run [a,b): subgroup-strided, 4/2/1-deep ladder
        f32x4 acc = (f32x4)0.f;
        int o = a + g;
        for (; o + 24 < b; o += 32) {
            const int s = base + o;
            const float w0 = __builtin_nontemporal_load(w + s);
            const float w1 = __builtin_nontemporal_load(w + s + 8);
            const float w2 = __builtin_nontemporal_load(w + s + 16);
            const float w3 = __builtin_nontemporal_load(w + s + 24);
            const f32x4 v0 = __builtin_nontemporal_load(sem4 + (size_t)s * 8 + q);
            const f32x4 v1 = __builtin_nontemporal_load(sem4 + (size_t)(s + 8)  * 8 + q);
            const f32x4 v2 = __builtin_nontemporal_load(sem4 + (size_t)(s + 16) * 8 + q);
            const f32x4 v3 = __builtin_nontemporal_load(sem4 + (size_t)(s + 24) * 8 + q);
            acc += w0 * v0; acc += w1 * v1; acc += w2 * v2; acc += w3 * v3;
        }
        for (; o + 8 < b; o += 16) {
            const int s = base + o;
            const float w0 = __builtin_nontemporal_load(w + s);
            const float w1 = __builtin_nontemporal_load(w + s + 8);
            const f32x4 v0 = __builtin_nontemporal_load(sem4 + (size_t)s * 8 + q);
            const f32x4 v1 = __builtin_nontemporal_load(sem4 + (size_t)(s + 8) * 8 + q);
            acc += w0 * v0; acc += w1 * v1;
        }
        if (o < b) {
            const int s = base + o;
            const float w0 = __builtin_nontemporal_load(w + s);
            const f32x4 v0 = __builtin_nontemporal_load(sem4 + (size_t)s * 8 + q);
            acc += w0 * v0;
        }

        // reduce across the 8 sample subgroups (lane bits 3,4,5); wave = 64
        #pragma unroll
        for (int m = 8; m < 64; m <<= 1) {
            acc.x += __shfl_xor(acc.x, m, 64);
            acc.y += __shfl_xor(acc.y, m, 64);
            acc.z += __shfl_xor(acc.z, m, 64);
            acc.w += __shfl_xor(acc.w, m, 64);
        }

        const bool headcont = (a == 0)  && (rid == prev_id);  // ray extends left
        const bool tailcont = (b == CL) && (rid == next_id);  // ray extends right
        if (g == 0) {
            float* dst = out + (size_t)rid * 32 + q * 4;
            if (headcont | tailcont) {
                atomicAdd(dst + 0, acc.x);
                atomicAdd(dst + 1, acc.y);
                atomicAdd(dst + 2, acc.z);
                atomicAdd(dst + 3, acc.w);
            } else {
                __builtin_nontemporal_store(acc, reinterpret_cast<f32x4*>(dst));
            }
        }
        a = b;
    }
}

extern "C" void kernel_launch(void* const* d_in, const int* in_sizes, int n_in,
                              void* d_out, int out_size, void* d_ws, size_t ws_size,
                              hipStream_t stream) {
    const f32x4* sem4 = (const f32x4*)d_in[0];
    const float* w    = (const float*)d_in[1];
    const int*   ridx = (const int*)d_in[2];
    float*       out  = (float*)d_out;

    const int N = in_sizes[1];        // number of samples (weights is [N])

    // zero output: covers empty rays, clears poison, provides atomic base
    hipMemsetAsync(out, 0, (size_t)out_size * sizeof(float), stream);

    const int chunks = (N + CHUNK - 1) / CHUNK;
    const int blocks = (chunks + 3) / 4;     // 4 waves (chunks) per block
    SemanticRenderer_70205535421052_kernel<<<blocks, 256, 0, stream>>>(
        sem4, w, ridx, out, N);
}

// Round 8
// 108.455 us; speedup vs baseline: 1.1525x; 1.1525x over previous
//
#include <hip/hip_runtime.h>

// SemanticRenderer: out[r, c] = sum_{i: ray_indices[i]==r} weights[i] * semantics[i, c]
// semantics: [N, 32] f32, weights: [N] f32, ray_indices: [N] int32 (SORTED), out: [R, 32] f32
//
// Best-known structure (R4, 108.4 us ~ 82% of achievable copy BW):
// Pass 0: memset seg[] (int2 per ray) to 0 -> empty rays have start==end==0.
// Pass 1 (bounds): int4-vectorized scan of ridx; run boundaries write seg[ray].
// Pass 2 (render): one wave per ray; lane = 8*g + q; wave reads 8 rows x 128B
//   = 1 KiB coalesced per load; 4-deep software pipeline; NT hints on the
//   zero-reuse sem/w/out streams.
// Structural alternatives tried and regressed: ray-pairing (R5), persistent
// grid (R6), sample-centric ballot-scan (R7). Residual gap vs the 89-us
// compulsory-traffic floor is short-segment latency, not over-fetch.

typedef float  f32x4 __attribute__((ext_vector_type(4)));

__global__ __launch_bounds__(256) void sr_bounds_kernel(
    const int* __restrict__ ridx, int2* __restrict__ seg, int N)
{
    const int t  = blockIdx.x * blockDim.x + threadIdx.x;
    const int i4 = t * 4;
    if (i4 >= N) return;

    if (i4 + 4 <= N) {
        const int4 v = *reinterpret_cast<const int4*>(ridx + i4);
        const int prev = (i4 == 0) ? -1 : ridx[i4 - 1];
        const int tail = (i4 + 4 < N) ? ridx[i4 + 4] : -2;   // -2 matches no ray id
        if (v.x != prev) { seg[v.x].x = i4;     if (prev >= 0) seg[prev].y = i4; }
        if (v.y != v.x)  { seg[v.y].x = i4 + 1; seg[v.x].y = i4 + 1; }
        if (v.z != v.y)  { seg[v.z].x = i4 + 2; seg[v.y].y = i4 + 2; }
        if (v.w != v.z)  { seg[v.w].x = i4 + 3; seg[v.z].y = i4 + 3; }
        if (v.w != tail) { seg[v.w].y = i4 + 4; }
    } else {
        for (int i = i4; i < N; ++i) {
            const int r    = ridx[i];
            const int prev = (i == 0) ? -1 : ridx[i - 1];
            const int next = (i == N - 1) ? -2 : ridx[i + 1];
            if (r != prev) seg[r].x = i;
            if (r != next) seg[r].y = i + 1;
        }
    }
}

__global__ __launch_bounds__(256) void SemanticRenderer_70205535421052_kernel(
    const f32x4* __restrict__ sem4,    // [N*8] (N rows of 8 float4)
    const float* __restrict__ w,       // [N]
    const int2*  __restrict__ seg,     // [R] (start, end); start==end for empty
    f32x4*       __restrict__ out4,    // [R*8]
    int R)
{
    const int wave = threadIdx.x >> 6;
    const int lane = threadIdx.x & 63;
    const int q    = lane & 7;         // class quad (classes 4q..4q+3)
    const int g    = lane >> 3;        // sample subgroup 0..7
    const int r    = blockIdx.x * 4 + wave;
    if (r >= R) return;

    const int2 se  = seg[r];           // one 8B broadcast load per wave
    const int  end = se.y;
    int s = se.x + g;

    f32x4 acc = (f32x4)0.f;

    // 4-deep pipeline: four independent 1 KiB wave-loads in flight
    for (; s + 24 < end; s += 32) {
        const float w0 = __builtin_nontemporal_load(w + s);
        const float w1 = __builtin_nontemporal_load(w + s + 8);
        const float w2 = __builtin_nontemporal_load(w + s + 16);
        const float w3 = __builtin_nontemporal_load(w + s + 24);
        const f32x4 v0 = __builtin_nontemporal_load(sem4 + (size_t)s * 8 + q);
        const f32x4 v1 = __builtin_nontemporal_load(sem4 + (size_t)(s + 8)  * 8 + q);
        const f32x4 v2 = __builtin_nontemporal_load(sem4 + (size_t)(s + 16) * 8 + q);
        const f32x4 v3 = __builtin_nontemporal_load(sem4 + (size_t)(s + 24) * 8 + q);
        acc += w0 * v0;
        acc += w1 * v1;
        acc += w2 * v2;
        acc += w3 * v3;
    }
    // 2-deep remainder
    for (; s + 8 < end; s += 16) {
        const float w0 = __builtin_nontemporal_load(w + s);
        const float w1 = __builtin_nontemporal_load(w + s + 8);
        const f32x4 v0 = __builtin_nontemporal_load(sem4 + (size_t)s * 8 + q);
        const f32x4 v1 = __builtin_nontemporal_load(sem4 + (size_t)(s + 8) * 8 + q);
        acc += w0 * v0;
        acc += w1 * v1;
    }
    if (s < end) {
        const float w0 = __builtin_nontemporal_load(w + s);
        const f32x4 v0 = __builtin_nontemporal_load(sem4 + (size_t)s * 8 + q);
        acc += w0 * v0;
    }

    // reduce across the 8 sample subgroups (lane bits 3,4,5); wave = 64 lanes
    #pragma unroll
    for (int m = 8; m < 64; m <<= 1) {
        acc.x += __shfl_xor(acc.x, m, 64);
        acc.y += __shfl_xor(acc.y, m, 64);
        acc.z += __shfl_xor(acc.z, m, 64);
        acc.w += __shfl_xor(acc.w, m, 64);
    }

    if (g == 0) __builtin_nontemporal_store(acc, out4 + (size_t)r * 8 + q);
}

extern "C" void kernel_launch(void* const* d_in, const int* in_sizes, int n_in,
                              void* d_out, int out_size, void* d_ws, size_t ws_size,
                              hipStream_t stream) {
    const f32x4* sem4 = (const f32x4*)d_in[0];
    const float* w    = (const float*)d_in[1];
    const int*   ridx = (const int*)d_in[2];
    f32x4*       out4 = (f32x4*)d_out;

    const int N = in_sizes[1];        // number of samples (weights is [N])
    const int R = out_size / 32;      // number of rays (out is [R,32])

    int2* seg = (int2*)d_ws;          // [R] (start, end)

    // start==end==0 for rays never written (empty) -> loop skipped -> zeros stored
    hipMemsetAsync(seg, 0, (size_t)R * sizeof(int2), stream);

    const int bthreads = (N + 3) / 4;
    sr_bounds_kernel<<<(bthreads + 255) / 256, 256, 0, stream>>>(ridx, seg, N);

    const int blocks = (R + 3) / 4;   // 4 rays (waves) per 256-thread block
    SemanticRenderer_70205535421052_kernel<<<blocks, 256, 0, stream>>>(
        sem4, w, seg, out4, R);
}

// Round 9
// 103.000 us; speedup vs baseline: 1.2135x; 1.0530x over previous
//
#include <hip/hip_runtime.h>

// SemanticRenderer: out[r, c] = sum_{i: ray_indices[i]==r} weights[i] * semantics[i, c]
// semantics: [N, 32] f32, weights: [N] f32, ray_indices: [N] int32 (SORTED), out: [R, 32] f32
//
// 2-dispatch pipeline (memset folded into bounds pass):
// Pass 1 (bounds): int4-vectorized scan of ridx; at each run transition a->b
//   write seg[a].y, seg[b].x, and gap-fill seg[x]={pos,pos} for empty rays
//   x in (a,b) (unique writer per entry: each gap belongs to one transition).
//   Head/tail threads fill [0, ridx[0]) and (ridx[N-1], R).
// Pass 2 (render, unchanged R4 structure = best known): one wave per ray;
//   lane = 8*g + q; 1 KiB coalesced per load step; 4/2/1-deep ladder; NT
//   hints on the zero-reuse sem/w/out streams. Empty rays: start==end -> 0.
// Structural alternatives tried and regressed: ray-pairing, persistent grid,
// sample-centric ballot-scan. Residual vs the ~89-us compulsory floor is
// short-segment latency, not over-fetch.

typedef float  f32x4 __attribute__((ext_vector_type(4)));

__global__ __launch_bounds__(256) void sr_bounds_kernel(
    const int* __restrict__ ridx, int2* __restrict__ seg, int N, int R)
{
    const int t  = blockIdx.x * blockDim.x + threadIdx.x;
    const int i4 = t * 4;
    if (i4 >= N) return;

    if (i4 + 4 <= N) {
        const int4 v = *reinterpret_cast<const int4*>(ridx + i4);
        const int prev = (i4 == 0) ? -1 : ridx[i4 - 1];
        const int tail = (i4 + 4 < N) ? ridx[i4 + 4] : -2;   // -2 matches no ray id
        if (v.x != prev) {
            seg[v.x].x = i4;
            if (prev >= 0) seg[prev].y = i4;
            for (int x = prev + 1; x < v.x; ++x) seg[x] = make_int2(i4, i4);
        }
        if (v.y != v.x) {
            seg[v.y].x = i4 + 1; seg[v.x].y = i4 + 1;
            for (int x = v.x + 1; x < v.y; ++x) seg[x] = make_int2(i4 + 1, i4 + 1);
        }
        if (v.z != v.y) {
            seg[v.z].x = i4 + 2; seg[v.y].y = i4 + 2;
            for (int x = v.y + 1; x < v.z; ++x) seg[x] = make_int2(i4 + 2, i4 + 2);
        }
        if (v.w != v.z) {
            seg[v.w].x = i4 + 3; seg[v.z].y = i4 + 3;
            for (int x = v.z + 1; x < v.w; ++x) seg[x] = make_int2(i4 + 3, i4 + 3);
        }
        if (v.w != tail) {
            seg[v.w].y = i4 + 4;
            if (tail == -2)   // global end: fill rays after the last id
                for (int x = v.w + 1; x < R; ++x) seg[x] = make_int2(N, N);
        }
    } else {
        // scalar tail (N % 4 != 0)
        for (int i = i4; i < N; ++i) {
            const int r    = ridx[i];
            const int prev = (i == 0) ? -1 : ridx[i - 1];
            const int next = (i == N - 1) ? -2 : ridx[i + 1];
            if (r != prev) {
                seg[r].x = i;
                for (int x = prev + 1; x < r; ++x) seg[x] = make_int2(i, i);
            }
            if (r != next) {
                seg[r].y = i + 1;
                if (next == -2)
                    for (int x = r + 1; x < R; ++x) seg[x] = make_int2(N, N);
            }
        }
    }
}

__global__ __launch_bounds__(256) void SemanticRenderer_70205535421052_kernel(
    const f32x4* __restrict__ sem4,    // [N*8] (N rows of 8 float4)
    const float* __restrict__ w,       // [N]
    const int2*  __restrict__ seg,     // [R] (start, end); start==end for empty
    f32x4*       __restrict__ out4,    // [R*8]
    int R)
{
    const int wave = threadIdx.x >> 6;
    const int lane = threadIdx.x & 63;
    const int q    = lane & 7;         // class quad (classes 4q..4q+3)
    const int g    = lane >> 3;        // sample subgroup 0..7
    const int r    = blockIdx.x * 4 + wave;
    if (r >= R) return;

    const int2 se  = seg[r];           // one 8B broadcast load per wave
    const int  end = se.y;
    int s = se.x + g;

    f32x4 acc = (f32x4)0.f;

    // 4-deep pipeline: four independent 1 KiB wave-loads in flight
    for (; s + 24 < end; s += 32) {
        const float w0 = __builtin_nontemporal_load(w + s);
        const float w1 = __builtin_nontemporal_load(w + s + 8);
        const float w2 = __builtin_nontemporal_load(w + s + 16);
        const float w3 = __builtin_nontemporal_load(w + s + 24);
        const f32x4 v0 = __builtin_nontemporal_load(sem4 + (size_t)s * 8 + q);
        const f32x4 v1 = __builtin_nontemporal_load(sem4 + (size_t)(s + 8)  * 8 + q);
        const f32x4 v2 = __builtin_nontemporal_load(sem4 + (size_t)(s + 16) * 8 + q);
        const f32x4 v3 = __builtin_nontemporal_load(sem4 + (size_t)(s + 24) * 8 + q);
        acc += w0 * v0;
        acc += w1 * v1;
        acc += w2 * v2;
        acc += w3 * v3;
    }
    // 2-deep remainder
    for (; s + 8 < end; s += 16) {
        const float w0 = __builtin_nontemporal_load(w + s);
        const float w1 = __builtin_nontemporal_load(w + s + 8);
        const f32x4 v0 = __builtin_nontemporal_load(sem4 + (size_t)s * 8 + q);
        const f32x4 v1 = __builtin_nontemporal_load(sem4 + (size_t)(s + 8) * 8 + q);
        acc += w0 * v0;
        acc += w1 * v1;
    }
    if (s < end) {
        const float w0 = __builtin_nontemporal_load(w + s);
        const f32x4 v0 = __builtin_nontemporal_load(sem4 + (size_t)s * 8 + q);
        acc += w0 * v0;
    }

    // reduce across the 8 sample subgroups (lane bits 3,4,5); wave = 64 lanes
    #pragma unroll
    for (int m = 8; m < 64; m <<= 1) {
        acc.x += __shfl_xor(acc.x, m, 64);
        acc.y += __shfl_xor(acc.y, m, 64);
        acc.z += __shfl_xor(acc.z, m, 64);
        acc.w += __shfl_xor(acc.w, m, 64);
    }

    if (g == 0) __builtin_nontemporal_store(acc, out4 + (size_t)r * 8 + q);
}

extern "C" void kernel_launch(void* const* d_in, const int* in_sizes, int n_in,
                              void* d_out, int out_size, void* d_ws, size_t ws_size,
                              hipStream_t stream) {
    const f32x4* sem4 = (const f32x4*)d_in[0];
    const float* w    = (const float*)d_in[1];
    const int*   ridx = (const int*)d_in[2];
    f32x4*       out4 = (f32x4*)d_out;

    const int N = in_sizes[1];        // number of samples (weights is [N])
    const int R = out_size / 32;      // number of rays (out is [R,32])

    int2* seg = (int2*)d_ws;          // [R] (start, end); fully written by bounds pass

    const int bthreads = (N + 3) / 4;
    sr_bounds_kernel<<<(bthreads + 255) / 256, 256, 0, stream>>>(ridx, seg, N, R);

    const int blocks = (R + 3) / 4;   // 4 rays (waves) per 256-thread block
    SemanticRenderer_70205535421052_kernel<<<blocks, 256, 0, stream>>>(
        sem4, w, seg, out4, R);
}